// Round 10
// baseline (159.568 us; speedup 1.0000x reference)
//
#include <hip/hip_runtime.h>
#include <hip/hip_bf16.h>
#include <stdint.h>

#define AS1 __attribute__((address_space(1)))
#define AS3 __attribute__((address_space(3)))

typedef __bf16 bf16x8 __attribute__((ext_vector_type(8)));
typedef float  f32x4  __attribute__((ext_vector_type(4)));
typedef unsigned short ushort8v __attribute__((ext_vector_type(8)));
typedef unsigned short ushort4v __attribute__((ext_vector_type(4)));
typedef short short8v __attribute__((ext_vector_type(8)));
typedef short short4v __attribute__((ext_vector_type(4)));

__device__ __forceinline__ unsigned short f2bf(float f) {
    unsigned int u = __float_as_uint(f);
    u += 0x7fffu + ((u >> 16) & 1u);           // round-to-nearest-even
    return (unsigned short)(u >> 16);
}
__device__ __forceinline__ unsigned int pk2bf(float a, float b) {
    __hip_bfloat162 h = __float22bfloat162_rn(make_float2(a, b));  // x->low short
    unsigned int u;
    __builtin_memcpy(&u, &h, 4);
    return u;
}
__device__ __forceinline__ void g2lds16(const void* gp, void* lp) {
    __builtin_amdgcn_global_load_lds((AS1 void*)gp, (AS3 void*)lp, 16, 0, 0);
}
#define E2(x) __builtin_amdgcn_exp2f(x)

// ---------------- cast fp32 -> bf16 (x, Wq, Wk, Wv in one launch) -----------
__global__ __launch_bounds__(256) void cast_all(const float* __restrict__ x,
                                                const float* __restrict__ w0,
                                                const float* __restrict__ w1,
                                                const float* __restrict__ w2,
                                                unsigned short* __restrict__ xb,
                                                unsigned short* __restrict__ wc) {
    int id = blockIdx.x;
    const float* s;
    unsigned short* d;
    int base;
    if (id < 4096) { s = x; d = xb; base = id; }
    else {
        int z = (id - 4096) >> 10;
        s = (z == 0) ? w0 : (z == 1) ? w1 : w2;
        d = wc + (size_t)z * 1048576;
        base = (id - 4096) & 1023;
    }
    int i = (base * 256 + threadIdx.x) * 4;
    float4 v = *(const float4*)(s + i);
    ushort4v o = { f2bf(v.x), f2bf(v.y), f2bf(v.z), f2bf(v.w) };
    *(ushort4v*)(d + i) = o;
}

// ---------------- QKV GEMM: X @ W^T (NT), dbuf single-barrier, swizzled -----
// R9-validated pipeline: [barrier; stage(k+1); compute(k)] — the vmcnt drain
// at the barrier waits on loads that had a full compute phase to land.
// LDS 4-slot XOR granule swizzle: slot s of row r holds global granule
// s^(r&3) (staging lane l fetches granule (l&3)^((l>>2)&3)); readers use
// quad^(cl&3) -> A/B-frag ds_read_b128 drops from 8-way to 4-way conflicts.
// Q (z=0) pre-scaled by 0.125*log2(e) so attn can exp2 scores directly.
__global__ __launch_bounds__(256) void gemm_qkv(const unsigned short* __restrict__ X,
                                                const unsigned short* __restrict__ W,
                                                unsigned short* __restrict__ QKV) {
    const int K = 1024, N = 1024;
    const int z = blockIdx.z;
    const unsigned short* A = X;
    const unsigned short* B = W + (size_t)z * (1024 * 1024);
    unsigned short* C = QKV + (size_t)z * (4096 * 1024);
    const float qs = (z == 0) ? 0.18033688011112042f : 1.0f;

    const int m0 = blockIdx.y * 128;
    const int n0 = blockIdx.x * 128;

    __shared__ unsigned short As[2][128 * 32];
    __shared__ unsigned short Bs[2][128 * 32];

    const int t = threadIdx.x;
    const int w = t >> 6;
    const int l = t & 63;
    const int wm = (w >> 1) * 64;
    const int wn = (w & 1) * 64;
    const int cl = l & 15;
    const int quad = l >> 4;

    const int srow = w * 16 + (l >> 2);
    const int scol = ((l & 3) ^ ((l >> 2) & 3)) * 8;   // swizzled source granule
    const int rsw = (cl & 3);                          // reader row&3

    f32x4 acc[4][4] = {};

    // stage k-chunk 0 into buf 0
    g2lds16(A + (size_t)(m0 + srow) * K + scol,      &As[0][w * 512]);
    g2lds16(A + (size_t)(m0 + 64 + srow) * K + scol, &As[0][2048 + w * 512]);
    g2lds16(B + (size_t)(n0 + srow) * K + scol,      &Bs[0][w * 512]);
    g2lds16(B + (size_t)(n0 + 64 + srow) * K + scol, &Bs[0][2048 + w * 512]);

    for (int kc = 0; kc < 32; ++kc) {
        __syncthreads();                               // buf[kc&1] ready
        if (kc + 1 < 32) {
            const int k0 = (kc + 1) * 32;
            unsigned short* a = &As[(kc + 1) & 1][0];
            unsigned short* b = &Bs[(kc + 1) & 1][0];
            g2lds16(A + (size_t)(m0 + srow) * K + k0 + scol,      a + w * 512);
            g2lds16(A + (size_t)(m0 + 64 + srow) * K + k0 + scol, a + 2048 + w * 512);
            g2lds16(B + (size_t)(n0 + srow) * K + k0 + scol,      b + w * 512);
            g2lds16(B + (size_t)(n0 + 64 + srow) * K + k0 + scol, b + 2048 + w * 512);
        }
        const unsigned short* Al = &As[kc & 1][0];
        const unsigned short* Bl = &Bs[kc & 1][0];

        bf16x8 af[4], bfr[4];
        #pragma unroll
        for (int i = 0; i < 4; ++i)
            af[i] = *(const bf16x8*)(Al + (wm + i * 16 + cl) * 32 + ((quad ^ rsw) * 8));
        #pragma unroll
        for (int j = 0; j < 4; ++j)
            bfr[j] = *(const bf16x8*)(Bl + (wn + j * 16 + cl) * 32 + ((quad ^ rsw) * 8));
        #pragma unroll
        for (int i = 0; i < 4; ++i)
            #pragma unroll
            for (int j = 0; j < 4; ++j)
                acc[i][j] = __builtin_amdgcn_mfma_f32_16x16x32_bf16(af[i], bfr[j], acc[i][j], 0, 0, 0);
    }

    #pragma unroll
    for (int i = 0; i < 4; ++i) {
        #pragma unroll
        for (int r = 0; r < 4; ++r) {
            size_t row = (size_t)(m0 + wm + i * 16 + quad * 4 + r);
            #pragma unroll
            for (int j = 0; j < 4; ++j)
                C[row * N + (n0 + wn + j * 16 + cl)] = f2bf(acc[i][j][r] * qs);
        }
    }
}

// ---------------- V swizzle to VT3 (per bh) ---------------------------------
// VT3 element (tau, d) at (tau>>4)*1024 + (d&15)*64 + ((tau>>2)&3)*16
//                        + (d>>4)*4 + (tau&3)
__global__ __launch_bounds__(256) void vtrans(const unsigned short* __restrict__ Vn,
                                              unsigned short* __restrict__ V3) {
    const int bh = blockIdx.y;
    const int T0 = blockIdx.x * 128;
    __shared__ unsigned short L[128 * 72];
    const int t = threadIdx.x;

    const unsigned short* src = Vn + (size_t)bh * 131072 + (size_t)T0 * 64;
    #pragma unroll
    for (int p = 0; p < 4; ++p) {
        int r = p * 32 + (t >> 3), c = (t & 7) * 8;
        *(ushort8v*)(L + r * 72 + c) = *(const ushort8v*)(src + (size_t)r * 64 + c);
    }
    __syncthreads();
    unsigned short* dst = V3 + (size_t)bh * 131072 + (size_t)(T0 >> 4) * 1024;
    #pragma unroll
    for (int p = 0; p < 2; ++p) {
        int item = p * 256 + t;                 // 512 items: kb(8) x cl(16) x qk(4)
        int kb = item >> 6, cl = (item >> 2) & 15, qk = item & 3;
        ushort8v a, b;
        #pragma unroll
        for (int u = 0; u < 8; ++u) {
            int dt = u >> 2, j = u & 3;
            a[u] = L[(kb * 16 + qk * 4 + j) * 72 + dt * 16 + cl];
            b[u] = L[(kb * 16 + qk * 4 + j) * 72 + (dt + 2) * 16 + cl];
        }
        unsigned short* dp = dst + kb * 1024 + cl * 64 + qk * 16;
        *(ushort8v*)(dp) = a;
        *(ushort8v*)(dp + 8) = b;
    }
}

// ---------------- Flash attention: band-merged LDS pipeline ------------------
// Block (4 waves) owns band pair (pp, 31-pp); the short band's kv chunks are
// a PREFIX of the long band's, so both bands share ONE staged K/V stream:
// per chunk, compute long band always, short band while c <= pp. Barriers
// drop to nchL (17..32) per block for 33 compute-chunks; up to 48 MFMAs per
// barrier. Wave w = 16-row strip of each band, complete output (no combine).
// LDS dbuf [barrier; stage(c+1); compute(c)] (R9-validated). XCD-pinned.
__global__ __launch_bounds__(256) void attn(const unsigned short* __restrict__ QK,
                                            const unsigned short* __restrict__ V3,
                                            float* __restrict__ Out) {
    const int id = blockIdx.x;
    const int bh = (id & 7) * 4 + ((id >> 3) & 3);     // 4 bh per XCD
    const int pp = id >> 5;                            // band-pair 0..15
    const int t = threadIdx.x;
    const int w = t >> 6;
    const int l = t & 63;
    const int cl = l & 15;
    const int quad = l >> 4;
    const int c7 = cl & 7;

    const size_t bhoff = (size_t)bh * 131072;
    const unsigned short* Qb = QK + bhoff;
    const unsigned short* Kb = QK + (size_t)4194304 + bhoff;
    const unsigned short* Vb = V3 + bhoff;
    float* Ob = Out + bhoff;

    __shared__ unsigned short KVs[2][8192];            // per buf: K 4096 | V 4096

    // staging constants (R9-verified swizzle)
    const int sg0 = t, sg1 = 256 + t;
    const int kO0 = (sg0 >> 3) * 64 + (((sg0 & 7) ^ ((sg0 >> 3) & 7)) * 8);
    const int kO1 = (sg1 >> 3) * 64 + (((sg1 & 7) ^ ((sg1 >> 3) & 7)) * 8);
    const int wg0 = sg0 & 63, wg1 = sg1 & 63;
    const int vO0 = (sg0 >> 6) * 512 + ((wg0 ^ ((wg0 >> 3) & 7)) * 8);
    const int vO1 = (sg1 >> 6) * 512 + ((wg1 ^ ((wg1 >> 3) & 7)) * 8);
    const int lB0 = w * 512;                           // shorts (wave-uniform)
    const int lB1 = 2048 + w * 512;

    // read offsets (R9-verified)
    const int oK0 = cl * 64 + (((quad)     ^ c7) * 8);
    const int oK1 = cl * 64 + (((quad + 4) ^ c7) * 8);
    const int oV0 = cl * 64 + (((quad * 2)     ^ c7) * 8);
    const int oV1 = cl * 64 + (((quad * 2 + 1) ^ c7) * 8);

    const int mrel = w * 16 + cl;                      // diag row rel. chunk base

    const int bL = 31 - pp;                            // long band
    const int nchL = 32 - pp;
    const int m0L = bL * 64 + w * 16;
    const int m0S = pp * 64 + w * 16;

    bf16x8 qfL0, qfL1, qfS0, qfS1;
    {
        const unsigned short* qa = Qb + (size_t)(m0L + cl) * 64 + quad * 8;
        qfL0 = *(const bf16x8*)(qa);
        qfL1 = *(const bf16x8*)(qa + 32);
        const unsigned short* qs = Qb + (size_t)(m0S + cl) * 64 + quad * 8;
        qfS0 = *(const bf16x8*)(qs);
        qfS1 = *(const bf16x8*)(qs + 32);
    }

    f32x4 oL[4] = {}, oS[4] = {};
    float lpL = 0.f, lpS = 0.f;

    // stage chunk 0 into buf 0
    {
        unsigned short* s = &KVs[0][0];
        g2lds16(Kb + kO0, s + lB0);
        g2lds16(Kb + kO1, s + lB1);
        g2lds16(Vb + vO0, s + 4096 + lB0);
        g2lds16(Vb + vO1, s + 4096 + lB1);
    }

    for (int c = 0; c < nchL; ++c) {
        __syncthreads();                               // buf[c&1] ready
        if (c + 1 < nchL) {
            const unsigned short* kg = Kb + (size_t)(c + 1) * 4096;
            const unsigned short* vg = Vb + (size_t)(c + 1) * 4096;
            unsigned short* s = &KVs[(c + 1) & 1][0];
            g2lds16(kg + kO0, s + lB0);
            g2lds16(kg + kO1, s + lB1);
            g2lds16(vg + vO0, s + 4096 + lB0);
            g2lds16(vg + vO1, s + 4096 + lB1);
        }
        const unsigned short* Kl = &KVs[c & 1][0];
        const unsigned short* Vl = Kl + 4096;
        const bool doS = (c <= pp);

        // K fragments (shared by both bands)
        bf16x8 kf0[4], kf1[4];
        #pragma unroll
        for (int kt = 0; kt < 4; ++kt) {
            kf0[kt] = *(const bf16x8*)(Kl + kt * 1024 + oK0);
            kf1[kt] = *(const bf16x8*)(Kl + kt * 1024 + oK1);
        }

        // S^T: lane holds (kv = kt*16 + quad*4 + r, m = m0 + cl)
        f32x4 stL[4] = {};
        #pragma unroll
        for (int kt = 0; kt < 4; ++kt) {
            stL[kt] = __builtin_amdgcn_mfma_f32_16x16x32_bf16(kf0[kt], qfL0, stL[kt], 0, 0, 0);
            stL[kt] = __builtin_amdgcn_mfma_f32_16x16x32_bf16(kf1[kt], qfL1, stL[kt], 0, 0, 0);
        }
        f32x4 stS[4] = {};
        if (doS) {
            #pragma unroll
            for (int kt = 0; kt < 4; ++kt) {
                stS[kt] = __builtin_amdgcn_mfma_f32_16x16x32_bf16(kf0[kt], qfS0, stS[kt], 0, 0, 0);
                stS[kt] = __builtin_amdgcn_mfma_f32_16x16x32_bf16(kf1[kt], qfS1, stS[kt], 0, 0, 0);
            }
        }

        short4v pbL[4], pbS[4];
        {
            const bool mL = (c == nchL - 1);
            #pragma unroll
            for (int kt = 0; kt < 4; ++kt) {
                float p0, p1, p2, p3;
                if (mL) {
                    const int lk = kt * 16 + quad * 4;
                    p0 = (lk     <= mrel) ? E2(stL[kt][0]) : 0.f;
                    p1 = (lk + 1 <= mrel) ? E2(stL[kt][1]) : 0.f;
                    p2 = (lk + 2 <= mrel) ? E2(stL[kt][2]) : 0.f;
                    p3 = (lk + 3 <= mrel) ? E2(stL[kt][3]) : 0.f;
                } else {
                    p0 = E2(stL[kt][0]); p1 = E2(stL[kt][1]);
                    p2 = E2(stL[kt][2]); p3 = E2(stL[kt][3]);
                }
                lpL += (p0 + p1) + (p2 + p3);
                uint2 u = { pk2bf(p0, p1), pk2bf(p2, p3) };
                __builtin_memcpy(&pbL[kt], &u, 8);
            }
        }
        if (doS) {
            const bool mS = (c == pp);
            #pragma unroll
            for (int kt = 0; kt < 4; ++kt) {
                float p0, p1, p2, p3;
                if (mS) {
                    const int lk = kt * 16 + quad * 4;
                    p0 = (lk     <= mrel) ? E2(stS[kt][0]) : 0.f;
                    p1 = (lk + 1 <= mrel) ? E2(stS[kt][1]) : 0.f;
                    p2 = (lk + 2 <= mrel) ? E2(stS[kt][2]) : 0.f;
                    p3 = (lk + 3 <= mrel) ? E2(stS[kt][3]) : 0.f;
                } else {
                    p0 = E2(stS[kt][0]); p1 = E2(stS[kt][1]);
                    p2 = E2(stS[kt][2]); p3 = E2(stS[kt][3]);
                }
                lpS += (p0 + p1) + (p2 + p3);
                uint2 u = { pk2bf(p0, p1), pk2bf(p2, p3) };
                __builtin_memcpy(&pbS[kt], &u, 8);
            }
        }

        // O^T += V^T . P^T (16x16x16); V frags read once, used by both bands
        #pragma unroll
        for (int kt = 0; kt < 4; ++kt) {
            short8v v0 = *(const short8v*)(Vl + kt * 1024 + oV0);  // dt 0,1
            short8v v1 = *(const short8v*)(Vl + kt * 1024 + oV1);  // dt 2,3
            short4v a0 = __builtin_shufflevector(v0, v0, 0, 1, 2, 3);
            short4v a1 = __builtin_shufflevector(v0, v0, 4, 5, 6, 7);
            short4v a2 = __builtin_shufflevector(v1, v1, 0, 1, 2, 3);
            short4v a3 = __builtin_shufflevector(v1, v1, 4, 5, 6, 7);
            oL[0] = __builtin_amdgcn_mfma_f32_16x16x16bf16_1k(a0, pbL[kt], oL[0], 0, 0, 0);
            oL[1] = __builtin_amdgcn_mfma_f32_16x16x16bf16_1k(a1, pbL[kt], oL[1], 0, 0, 0);
            oL[2] = __builtin_amdgcn_mfma_f32_16x16x16bf16_1k(a2, pbL[kt], oL[2], 0, 0, 0);
            oL[3] = __builtin_amdgcn_mfma_f32_16x16x16bf16_1k(a3, pbL[kt], oL[3], 0, 0, 0);
            if (doS) {
                oS[0] = __builtin_amdgcn_mfma_f32_16x16x16bf16_1k(a0, pbS[kt], oS[0], 0, 0, 0);
                oS[1] = __builtin_amdgcn_mfma_f32_16x16x16bf16_1k(a1, pbS[kt], oS[1], 0, 0, 0);
                oS[2] = __builtin_amdgcn_mfma_f32_16x16x16bf16_1k(a2, pbS[kt], oS[2], 0, 0, 0);
                oS[3] = __builtin_amdgcn_mfma_f32_16x16x16bf16_1k(a3, pbS[kt], oS[3], 0, 0, 0);
            }
        }
    }

    // epilogue: per-band quad row-sum + normalized write (m = m0+cl,
    // d = dt*16 + quad*4 + r)
    lpL += __shfl_xor(lpL, 16);
    lpL += __shfl_xor(lpL, 32);
    lpS += __shfl_xor(lpS, 16);
    lpS += __shfl_xor(lpS, 32);
    const float invL = 1.0f / lpL;
    const float invS = 1.0f / lpS;
    #pragma unroll
    for (int dt = 0; dt < 4; ++dt) {
        f32x4 r = oL[dt];
        r[0] *= invL; r[1] *= invL; r[2] *= invL; r[3] *= invL;
        *(f32x4*)(Ob + (size_t)(m0L + cl) * 64 + dt * 16 + quad * 4) = r;
        f32x4 q = oS[dt];
        q[0] *= invS; q[1] *= invS; q[2] *= invS; q[3] *= invS;
        *(f32x4*)(Ob + (size_t)(m0S + cl) * 64 + dt * 16 + quad * 4) = q;
    }
}

extern "C" void kernel_launch(void* const* d_in, const int* in_sizes, int n_in,
                              void* d_out, int out_size, void* d_ws, size_t ws_size,
                              hipStream_t stream) {
    const float* x  = (const float*)d_in[0];
    const float* Wq = (const float*)d_in[1];
    const float* Wk = (const float*)d_in[2];
    const float* Wv = (const float*)d_in[3];
    float* out = (float*)d_out;

    // ws: xb 8MB | wc 6MB | QKV natural 24MB | VT3 8MB = 46MB
    unsigned short* xb  = (unsigned short*)d_ws;
    unsigned short* wc  = xb + (size_t)4096 * 1024;
    unsigned short* qkv = wc + (size_t)3 * 1024 * 1024;
    unsigned short* vt  = qkv + (size_t)3 * 4096 * 1024;

    hipLaunchKernelGGL(cast_all, dim3(7168), dim3(256), 0, stream, x, Wq, Wk, Wv, xb, wc);
    hipLaunchKernelGGL(gemm_qkv, dim3(8, 32, 3), dim3(256), 0, stream, xb, wc, qkv);
    hipLaunchKernelGGL(vtrans, dim3(16, 32), dim3(256), 0, stream, qkv + (size_t)2 * 4096 * 1024, vt);
    hipLaunchKernelGGL(attn, dim3(512), dim3(256), 0, stream, qkv, vt, out);
}

// Round 12
// 156.159 us; speedup vs baseline: 1.0218x; 1.0218x over previous
//
#include <hip/hip_runtime.h>
#include <hip/hip_bf16.h>
#include <stdint.h>

#define AS1 __attribute__((address_space(1)))
#define AS3 __attribute__((address_space(3)))

typedef __bf16 bf16x8 __attribute__((ext_vector_type(8)));
typedef float  f32x4  __attribute__((ext_vector_type(4)));
typedef unsigned short ushort8v __attribute__((ext_vector_type(8)));
typedef unsigned short ushort4v __attribute__((ext_vector_type(4)));
typedef short short8v __attribute__((ext_vector_type(8)));
typedef short short4v __attribute__((ext_vector_type(4)));

__device__ __forceinline__ unsigned short f2bf(float f) {
    unsigned int u = __float_as_uint(f);
    u += 0x7fffu + ((u >> 16) & 1u);           // round-to-nearest-even
    return (unsigned short)(u >> 16);
}
__device__ __forceinline__ unsigned int pk2bf(float a, float b) {
    __hip_bfloat162 h = __float22bfloat162_rn(make_float2(a, b));  // x->low short
    unsigned int u;
    __builtin_memcpy(&u, &h, 4);
    return u;
}
__device__ __forceinline__ void g2lds16(const void* gp, void* lp) {
    __builtin_amdgcn_global_load_lds((AS1 void*)gp, (AS3 void*)lp, 16, 0, 0);
}
#define E2(x) __builtin_amdgcn_exp2f(x)

// ---------------- cast fp32 -> bf16 (x, Wq, Wk, Wv in one launch) -----------
__global__ __launch_bounds__(256) void cast_all(const float* __restrict__ x,
                                                const float* __restrict__ w0,
                                                const float* __restrict__ w1,
                                                const float* __restrict__ w2,
                                                unsigned short* __restrict__ xb,
                                                unsigned short* __restrict__ wc) {
    int id = blockIdx.x;
    const float* s;
    unsigned short* d;
    int base;
    if (id < 4096) { s = x; d = xb; base = id; }
    else {
        int z = (id - 4096) >> 10;
        s = (z == 0) ? w0 : (z == 1) ? w1 : w2;
        d = wc + (size_t)z * 1048576;
        base = (id - 4096) & 1023;
    }
    int i = (base * 256 + threadIdx.x) * 4;
    float4 v = *(const float4*)(s + i);
    ushort4v o = { f2bf(v.x), f2bf(v.y), f2bf(v.z), f2bf(v.w) };
    *(ushort4v*)(d + i) = o;
}

// ---------------- QKV GEMM: X @ W^T (NT), m97 structure (R9-exact) -----------
// R11 lesson: direct-VT3 write is impossible from this tiling (tau low bits
// come from the COLUMN head index; 4 consecutive tau span 2 blocks). V is
// written natural (coalesced); vtrans does the swizzle.
// Q (z=0) pre-scaled by 0.125*log2(e) so attn can exp2 scores directly.
__global__ __launch_bounds__(256) void gemm_qkv(const unsigned short* __restrict__ X,
                                                const unsigned short* __restrict__ W,
                                                unsigned short* __restrict__ QKV) {
    const int K = 1024, N = 1024;
    const int z = blockIdx.z;
    const unsigned short* A = X;
    const unsigned short* B = W + (size_t)z * (1024 * 1024);
    unsigned short* C = QKV + (size_t)z * (4096 * 1024);
    const float qs = (z == 0) ? 0.18033688011112042f : 1.0f;

    const int m0 = blockIdx.y * 128;
    const int n0 = blockIdx.x * 128;

    __shared__ unsigned short As[128 * 32];
    __shared__ unsigned short Bs[128 * 32];

    const int t = threadIdx.x;
    const int w = t >> 6;
    const int l = t & 63;
    const int wm = (w >> 1) * 64;
    const int wn = (w & 1) * 64;
    const int cl = l & 15;
    const int quad = l >> 4;

    const int srow = w * 16 + (l >> 2);
    const int scol = (l & 3) * 8;

    f32x4 acc[4][4] = {};

    for (int k0 = 0; k0 < K; k0 += 32) {
        g2lds16(A + (size_t)(m0 + srow) * K + k0 + scol,      As + w * 512);
        g2lds16(A + (size_t)(m0 + 64 + srow) * K + k0 + scol, As + 2048 + w * 512);
        g2lds16(B + (size_t)(n0 + srow) * K + k0 + scol,      Bs + w * 512);
        g2lds16(B + (size_t)(n0 + 64 + srow) * K + k0 + scol, Bs + 2048 + w * 512);
        __syncthreads();

        bf16x8 af[4], bfr[4];
        #pragma unroll
        for (int i = 0; i < 4; ++i)
            af[i] = *(const bf16x8*)(As + (wm + i * 16 + cl) * 32 + quad * 8);
        #pragma unroll
        for (int j = 0; j < 4; ++j)
            bfr[j] = *(const bf16x8*)(Bs + (wn + j * 16 + cl) * 32 + quad * 8);
        #pragma unroll
        for (int i = 0; i < 4; ++i)
            #pragma unroll
            for (int j = 0; j < 4; ++j)
                acc[i][j] = __builtin_amdgcn_mfma_f32_16x16x32_bf16(af[i], bfr[j], acc[i][j], 0, 0, 0);
        __syncthreads();
    }

    #pragma unroll
    for (int i = 0; i < 4; ++i) {
        #pragma unroll
        for (int r = 0; r < 4; ++r) {
            size_t row = (size_t)(m0 + wm + i * 16 + quad * 4 + r);
            #pragma unroll
            for (int j = 0; j < 4; ++j)
                C[row * N + (n0 + wn + j * 16 + cl)] = f2bf(acc[i][j][r] * qs);
        }
    }
}

// ---------------- V swizzle to VT3 (per bh) ---------------------------------
// VT3 element (tau, d) at (tau>>4)*1024 + (d&15)*64 + ((tau>>2)&3)*16
//                        + (d>>4)*4 + (tau&3)
__global__ __launch_bounds__(256) void vtrans(const unsigned short* __restrict__ Vn,
                                              unsigned short* __restrict__ V3) {
    const int bh = blockIdx.y;
    const int T0 = blockIdx.x * 128;
    __shared__ unsigned short L[128 * 72];
    const int t = threadIdx.x;

    const unsigned short* src = Vn + (size_t)bh * 131072 + (size_t)T0 * 64;
    #pragma unroll
    for (int p = 0; p < 4; ++p) {
        int r = p * 32 + (t >> 3), c = (t & 7) * 8;
        *(ushort8v*)(L + r * 72 + c) = *(const ushort8v*)(src + (size_t)r * 64 + c);
    }
    __syncthreads();
    unsigned short* dst = V3 + (size_t)bh * 131072 + (size_t)(T0 >> 4) * 1024;
    #pragma unroll
    for (int p = 0; p < 2; ++p) {
        int item = p * 256 + t;                 // 512 items: kb(8) x cl(16) x qk(4)
        int kb = item >> 6, cl = (item >> 2) & 15, qk = item & 3;
        ushort8v a, b;
        #pragma unroll
        for (int u = 0; u < 8; ++u) {
            int dt = u >> 2, j = u & 3;
            a[u] = L[(kb * 16 + qk * 4 + j) * 72 + dt * 16 + cl];
            b[u] = L[(kb * 16 + qk * 4 + j) * 72 + (dt + 2) * 16 + cl];
        }
        unsigned short* dp = dst + kb * 1024 + cl * 64 + qk * 16;
        *(ushort8v*)(dp) = a;
        *(ushort8v*)(dp + 8) = b;
    }
}

// ---------------- Flash attention: 32 Q-rows/wave, LDS pipeline --------------
// R9 structure (single-barrier dbuf, [barrier; stage(c+1); compute(c)]) with
// DOUBLED compute per LDS read: all 4 waves read identical K/V frags, so each
// wave owns 32 rows (two 16-row m-tiles) -> 16 ds_read_b128 feed 48 MFMAs
// (vs 24). Block = 128-row band; bands paired (pp, 15-pp): 34 staged chunks
// per block, uniform; grid 256 = 1 block/CU (g2lds16 staging needs no VGPRs,
// so the async prefetch cannot be allocator-sunk; it lands during compute).
// Wave-pair masking: waves 0-1 (rows +0..63) diagonal at chunk 2bb, skip
// 2bb+1; waves 2-3 (rows +64..127) diagonal at 2bb+1. In-diag row base
// mrel = 32*(w&1) + 16*mt + cl. XCD-pinned (4 bh/XCD).
__global__ __launch_bounds__(256) void attn(const unsigned short* __restrict__ QK,
                                            const unsigned short* __restrict__ V3,
                                            float* __restrict__ Out) {
    const int id = blockIdx.x;                         // 256 blocks
    const int bh = (id & 7) * 4 + ((id >> 3) & 3);     // 4 bh per XCD
    const int pp = id >> 5;                            // band-pair 0..7
    const int t = threadIdx.x;
    const int w = t >> 6;
    const int l = t & 63;
    const int cl = l & 15;
    const int quad = l >> 4;
    const int c7 = cl & 7;

    const size_t bhoff = (size_t)bh * 131072;
    const unsigned short* Qb = QK + bhoff;
    const unsigned short* Kb = QK + (size_t)4194304 + bhoff;
    const unsigned short* Vb = V3 + bhoff;
    float* Ob = Out + bhoff;

    __shared__ unsigned short KVs[2][8192];            // per buf: K 4096 | V 4096

    // staging offsets (R9-verified swizzle)
    const int sg0 = t, sg1 = 256 + t;
    const int kO0 = (sg0 >> 3) * 64 + (((sg0 & 7) ^ ((sg0 >> 3) & 7)) * 8);
    const int kO1 = (sg1 >> 3) * 64 + (((sg1 & 7) ^ ((sg1 >> 3) & 7)) * 8);
    const int wg0 = sg0 & 63, wg1 = sg1 & 63;
    const int vO0 = (sg0 >> 6) * 512 + ((wg0 ^ ((wg0 >> 3) & 7)) * 8);
    const int vO1 = (sg1 >> 6) * 512 + ((wg1 ^ ((wg1 >> 3) & 7)) * 8);
    const int lB0 = w * 512;                           // shorts (wave-uniform)
    const int lB1 = 2048 + w * 512;

    // read offsets (R9-verified)
    const int oK0 = cl * 64 + (((quad)     ^ c7) * 8);
    const int oK1 = cl * 64 + (((quad + 4) ^ c7) * 8);
    const int oV0 = cl * 64 + (((quad * 2)     ^ c7) * 8);
    const int oV1 = cl * 64 + (((quad * 2 + 1) ^ c7) * 8);

    const int mloc = 32 * (w & 1);                     // in-diag-chunk row base

    #pragma unroll 1                                   // R6 lesson: no state merge
    for (int hb = 0; hb < 2; ++hb) {
        const int bb = hb ? (15 - pp) : pp;            // 128-row band index
        const int nchB = 2 * bb + 2;                   // staged 64-kv chunks
        const int myLast = 2 * bb + (w >> 1);          // last chunk this wave computes
        const int m0w = bb * 128 + w * 32;

        bf16x8 qf[2][2];
        #pragma unroll
        for (int mt = 0; mt < 2; ++mt) {
            const unsigned short* qa = Qb + (size_t)(m0w + mt * 16 + cl) * 64 + quad * 8;
            qf[mt][0] = *(const bf16x8*)(qa);
            qf[mt][1] = *(const bf16x8*)(qa + 32);
        }

        f32x4 o[2][4] = {};
        float lp[2] = {0.f, 0.f};

        // stage chunk 0 into buf 0
        {
            unsigned short* s = &KVs[0][0];
            g2lds16(Kb + kO0, s + lB0);
            g2lds16(Kb + kO1, s + lB1);
            g2lds16(Vb + vO0, s + 4096 + lB0);
            g2lds16(Vb + vO1, s + 4096 + lB1);
        }

        for (int c = 0; c < nchB; ++c) {
            __syncthreads();                           // buf[c&1] ready
            if (c + 1 < nchB) {
                const unsigned short* kg = Kb + (size_t)(c + 1) * 4096;
                const unsigned short* vg = Vb + (size_t)(c + 1) * 4096;
                unsigned short* s = &KVs[(c + 1) & 1][0];
                g2lds16(kg + kO0, s + lB0);
                g2lds16(kg + kO1, s + lB1);
                g2lds16(vg + vO0, s + 4096 + lB0);
                g2lds16(vg + vO1, s + 4096 + lB1);
            }
            if (c > myLast) continue;                  // wave-uniform skip
            const unsigned short* Kl = &KVs[c & 1][0];
            const unsigned short* Vl = Kl + 4096;
            const bool masked = (c == myLast);

            // K fragments — shared by both m-tiles
            bf16x8 kf0[4], kf1[4];
            #pragma unroll
            for (int kt = 0; kt < 4; ++kt) {
                kf0[kt] = *(const bf16x8*)(Kl + kt * 1024 + oK0);
                kf1[kt] = *(const bf16x8*)(Kl + kt * 1024 + oK1);
            }

            // S^T: lane holds (kv = kt*16 + quad*4 + r, m = m0w + mt*16 + cl)
            f32x4 st[2][4] = {};
            #pragma unroll
            for (int mt = 0; mt < 2; ++mt)
                #pragma unroll
                for (int kt = 0; kt < 4; ++kt) {
                    st[mt][kt] = __builtin_amdgcn_mfma_f32_16x16x32_bf16(kf0[kt], qf[mt][0], st[mt][kt], 0, 0, 0);
                    st[mt][kt] = __builtin_amdgcn_mfma_f32_16x16x32_bf16(kf1[kt], qf[mt][1], st[mt][kt], 0, 0, 0);
                }

            short4v pb[2][4];
            #pragma unroll
            for (int mt = 0; mt < 2; ++mt) {
                const int mrel = mloc + mt * 16 + cl;
                #pragma unroll
                for (int kt = 0; kt < 4; ++kt) {
                    float p0, p1, p2, p3;
                    if (masked) {
                        const int lk = kt * 16 + quad * 4;
                        p0 = (lk     <= mrel) ? E2(st[mt][kt][0]) : 0.f;
                        p1 = (lk + 1 <= mrel) ? E2(st[mt][kt][1]) : 0.f;
                        p2 = (lk + 2 <= mrel) ? E2(st[mt][kt][2]) : 0.f;
                        p3 = (lk + 3 <= mrel) ? E2(st[mt][kt][3]) : 0.f;
                    } else {
                        p0 = E2(st[mt][kt][0]);
                        p1 = E2(st[mt][kt][1]);
                        p2 = E2(st[mt][kt][2]);
                        p3 = E2(st[mt][kt][3]);
                    }
                    lp[mt] += (p0 + p1) + (p2 + p3);
                    uint2 u = { pk2bf(p0, p1), pk2bf(p2, p3) };
                    __builtin_memcpy(&pb[mt][kt], &u, 8);
                }
            }

            // O^T += V^T . P^T (16x16x16); V frags read once per wave
            #pragma unroll
            for (int kt = 0; kt < 4; ++kt) {
                short8v v0 = *(const short8v*)(Vl + kt * 1024 + oV0);  // dt 0,1
                short8v v1 = *(const short8v*)(Vl + kt * 1024 + oV1);  // dt 2,3
                short4v a0 = __builtin_shufflevector(v0, v0, 0, 1, 2, 3);
                short4v a1 = __builtin_shufflevector(v0, v0, 4, 5, 6, 7);
                short4v a2 = __builtin_shufflevector(v1, v1, 0, 1, 2, 3);
                short4v a3 = __builtin_shufflevector(v1, v1, 4, 5, 6, 7);
                #pragma unroll
                for (int mt = 0; mt < 2; ++mt) {
                    o[mt][0] = __builtin_amdgcn_mfma_f32_16x16x16bf16_1k(a0, pb[mt][kt], o[mt][0], 0, 0, 0);
                    o[mt][1] = __builtin_amdgcn_mfma_f32_16x16x16bf16_1k(a1, pb[mt][kt], o[mt][1], 0, 0, 0);
                    o[mt][2] = __builtin_amdgcn_mfma_f32_16x16x16bf16_1k(a2, pb[mt][kt], o[mt][2], 0, 0, 0);
                    o[mt][3] = __builtin_amdgcn_mfma_f32_16x16x16bf16_1k(a3, pb[mt][kt], o[mt][3], 0, 0, 0);
                }
            }
        }
        __syncthreads();                               // buf reuse across bands

        // epilogue: quad row-sum + normalized write (m = m0w+mt*16+cl,
        // d = dt*16 + quad*4 + r)
        #pragma unroll
        for (int mt = 0; mt < 2; ++mt) {
            float s = lp[mt];
            s += __shfl_xor(s, 16);
            s += __shfl_xor(s, 32);
            const float inv = 1.0f / s;
            #pragma unroll
            for (int dt = 0; dt < 4; ++dt) {
                f32x4 r = o[mt][dt];
                r[0] *= inv; r[1] *= inv; r[2] *= inv; r[3] *= inv;
                *(f32x4*)(Ob + (size_t)(m0w + mt * 16 + cl) * 64 + dt * 16 + quad * 4) = r;
            }
        }
    }
}

extern "C" void kernel_launch(void* const* d_in, const int* in_sizes, int n_in,
                              void* d_out, int out_size, void* d_ws, size_t ws_size,
                              hipStream_t stream) {
    const float* x  = (const float*)d_in[0];
    const float* Wq = (const float*)d_in[1];
    const float* Wk = (const float*)d_in[2];
    const float* Wv = (const float*)d_in[3];
    float* out = (float*)d_out;

    // ws: xb 8MB | wc 6MB | QKV natural 24MB | VT3 8MB = 46MB
    unsigned short* xb  = (unsigned short*)d_ws;
    unsigned short* wc  = xb + (size_t)4096 * 1024;
    unsigned short* qkv = wc + (size_t)3 * 1024 * 1024;
    unsigned short* vt  = qkv + (size_t)3 * 4096 * 1024;

    hipLaunchKernelGGL(cast_all, dim3(7168), dim3(256), 0, stream, x, Wq, Wk, Wv, xb, wc);
    hipLaunchKernelGGL(gemm_qkv, dim3(8, 32, 3), dim3(256), 0, stream, xb, wc, qkv);
    hipLaunchKernelGGL(vtrans, dim3(16, 32), dim3(256), 0, stream, qkv + (size_t)2 * 4096 * 1024, vt);
    hipLaunchKernelGGL(attn, dim3(256), dim3(256), 0, stream, qkv, vt, out);
}

// Round 13
// 147.891 us; speedup vs baseline: 1.0790x; 1.0559x over previous
//
#include <hip/hip_runtime.h>
#include <hip/hip_bf16.h>
#include <stdint.h>

#define AS1 __attribute__((address_space(1)))
#define AS3 __attribute__((address_space(3)))

typedef __bf16 bf16x8 __attribute__((ext_vector_type(8)));
typedef float  f32x4  __attribute__((ext_vector_type(4)));
typedef unsigned short ushort8v __attribute__((ext_vector_type(8)));
typedef unsigned short ushort4v __attribute__((ext_vector_type(4)));
typedef short short8v __attribute__((ext_vector_type(8)));
typedef short short4v __attribute__((ext_vector_type(4)));

__device__ __forceinline__ unsigned short f2bf(float f) {
    unsigned int u = __float_as_uint(f);
    u += 0x7fffu + ((u >> 16) & 1u);           // round-to-nearest-even
    return (unsigned short)(u >> 16);
}
__device__ __forceinline__ unsigned int pk2bf(float a, float b) {
    __hip_bfloat162 h = __float22bfloat162_rn(make_float2(a, b));  // x->low short
    unsigned int u;
    __builtin_memcpy(&u, &h, 4);
    return u;
}
__device__ __forceinline__ void g2lds16(const void* gp, void* lp) {
    __builtin_amdgcn_global_load_lds((AS1 void*)gp, (AS3 void*)lp, 16, 0, 0);
}
#define E2(x) __builtin_amdgcn_exp2f(x)

// ---------------- cast fp32 -> bf16 (x, Wq, Wk, Wv in one launch) -----------
__global__ __launch_bounds__(256) void cast_all(const float* __restrict__ x,
                                                const float* __restrict__ w0,
                                                const float* __restrict__ w1,
                                                const float* __restrict__ w2,
                                                unsigned short* __restrict__ xb,
                                                unsigned short* __restrict__ wc) {
    int id = blockIdx.x;
    const float* s;
    unsigned short* d;
    int base;
    if (id < 4096) { s = x; d = xb; base = id; }
    else {
        int z = (id - 4096) >> 10;
        s = (z == 0) ? w0 : (z == 1) ? w1 : w2;
        d = wc + (size_t)z * 1048576;
        base = (id - 4096) & 1023;
    }
    int i = (base * 256 + threadIdx.x) * 4;
    float4 v = *(const float4*)(s + i);
    ushort4v o = { f2bf(v.x), f2bf(v.y), f2bf(v.z), f2bf(v.w) };
    *(ushort4v*)(d + i) = o;
}

// ---------------- QKV GEMM: X @ W^T (NT), m97 structure (R9-exact) -----------
// Q (z=0) pre-scaled by 0.125*log2(e) so attn can exp2 scores directly.
__global__ __launch_bounds__(256) void gemm_qkv(const unsigned short* __restrict__ X,
                                                const unsigned short* __restrict__ W,
                                                unsigned short* __restrict__ QKV) {
    const int K = 1024, N = 1024;
    const int z = blockIdx.z;
    const unsigned short* A = X;
    const unsigned short* B = W + (size_t)z * (1024 * 1024);
    unsigned short* C = QKV + (size_t)z * (4096 * 1024);
    const float qs = (z == 0) ? 0.18033688011112042f : 1.0f;

    const int m0 = blockIdx.y * 128;
    const int n0 = blockIdx.x * 128;

    __shared__ unsigned short As[128 * 32];
    __shared__ unsigned short Bs[128 * 32];

    const int t = threadIdx.x;
    const int w = t >> 6;
    const int l = t & 63;
    const int wm = (w >> 1) * 64;
    const int wn = (w & 1) * 64;
    const int cl = l & 15;
    const int quad = l >> 4;

    const int srow = w * 16 + (l >> 2);
    const int scol = (l & 3) * 8;

    f32x4 acc[4][4] = {};

    for (int k0 = 0; k0 < K; k0 += 32) {
        g2lds16(A + (size_t)(m0 + srow) * K + k0 + scol,      As + w * 512);
        g2lds16(A + (size_t)(m0 + 64 + srow) * K + k0 + scol, As + 2048 + w * 512);
        g2lds16(B + (size_t)(n0 + srow) * K + k0 + scol,      Bs + w * 512);
        g2lds16(B + (size_t)(n0 + 64 + srow) * K + k0 + scol, Bs + 2048 + w * 512);
        __syncthreads();

        bf16x8 af[4], bfr[4];
        #pragma unroll
        for (int i = 0; i < 4; ++i)
            af[i] = *(const bf16x8*)(As + (wm + i * 16 + cl) * 32 + quad * 8);
        #pragma unroll
        for (int j = 0; j < 4; ++j)
            bfr[j] = *(const bf16x8*)(Bs + (wn + j * 16 + cl) * 32 + quad * 8);
        #pragma unroll
        for (int i = 0; i < 4; ++i)
            #pragma unroll
            for (int j = 0; j < 4; ++j)
                acc[i][j] = __builtin_amdgcn_mfma_f32_16x16x32_bf16(af[i], bfr[j], acc[i][j], 0, 0, 0);
        __syncthreads();
    }

    #pragma unroll
    for (int i = 0; i < 4; ++i) {
        #pragma unroll
        for (int r = 0; r < 4; ++r) {
            size_t row = (size_t)(m0 + wm + i * 16 + quad * 4 + r);
            #pragma unroll
            for (int j = 0; j < 4; ++j)
                C[row * N + (n0 + wn + j * 16 + cl)] = f2bf(acc[i][j][r] * qs);
        }
    }
}

// ---------------- V swizzle to VT3 (per bh) ---------------------------------
// VT3 element (tau, d) at (tau>>4)*1024 + (d&15)*64 + ((tau>>2)&3)*16
//                        + (d>>4)*4 + (tau&3)
__global__ __launch_bounds__(256) void vtrans(const unsigned short* __restrict__ Vn,
                                              unsigned short* __restrict__ V3) {
    const int bh = blockIdx.y;
    const int T0 = blockIdx.x * 128;
    __shared__ unsigned short L[128 * 72];
    const int t = threadIdx.x;

    const unsigned short* src = Vn + (size_t)bh * 131072 + (size_t)T0 * 64;
    #pragma unroll
    for (int p = 0; p < 4; ++p) {
        int r = p * 32 + (t >> 3), c = (t & 7) * 8;
        *(ushort8v*)(L + r * 72 + c) = *(const ushort8v*)(src + (size_t)r * 64 + c);
    }
    __syncthreads();
    unsigned short* dst = V3 + (size_t)bh * 131072 + (size_t)(T0 >> 4) * 1024;
    #pragma unroll
    for (int p = 0; p < 2; ++p) {
        int item = p * 256 + t;                 // 512 items: kb(8) x cl(16) x qk(4)
        int kb = item >> 6, cl = (item >> 2) & 15, qk = item & 3;
        ushort8v a, b;
        #pragma unroll
        for (int u = 0; u < 8; ++u) {
            int dt = u >> 2, j = u & 3;
            a[u] = L[(kb * 16 + qk * 4 + j) * 72 + dt * 16 + cl];
            b[u] = L[(kb * 16 + qk * 4 + j) * 72 + (dt + 2) * 16 + cl];
        }
        unsigned short* dp = dst + kb * 1024 + cl * 64 + qk * 16;
        *(ushort8v*)(dp) = a;
        *(ushort8v*)(dp + 8) = b;
    }
}

// ---------------- Flash attention: 8-wave block, 128-row band, LDS pipeline --
// R12 post-mortem: 4-wave/128-row blocks = 1 wave/SIMD — dependency chains
// fully exposed. Fix: 512-thread blocks (8 waves x 16 rows = 128-row band),
// SAME shared K/V stream and single-barrier dbuf -> 2 waves/SIMD (R9's TLP)
// with R12's halved staging traffic. Bands paired (pp, 15-pp): 34 staged
// chunks per block, uniform over 256 blocks (1/CU). Diagonal: wave w masks
// at chunk 2bb+(w>>2), in-chunk row base (w&3)*16+cl; earlier waves skip the
// final chunk (wave-uniform continue). XCD-pinned (4 bh/XCD).
__global__ __launch_bounds__(512) void attn(const unsigned short* __restrict__ QK,
                                            const unsigned short* __restrict__ V3,
                                            float* __restrict__ Out) {
    const int id = blockIdx.x;                         // 256 blocks
    const int bh = (id & 7) * 4 + ((id >> 3) & 3);     // 4 bh per XCD
    const int pp = id >> 5;                            // band-pair 0..7
    const int t = threadIdx.x;                         // 0..511
    const int w = t >> 6;                              // wave 0..7
    const int l = t & 63;
    const int cl = l & 15;
    const int quad = l >> 4;
    const int c7 = cl & 7;

    const size_t bhoff = (size_t)bh * 131072;
    const unsigned short* Qb = QK + bhoff;
    const unsigned short* Kb = QK + (size_t)4194304 + bhoff;
    const unsigned short* Vb = V3 + bhoff;
    float* Ob = Out + bhoff;

    __shared__ unsigned short KVs[2][8192];            // per buf: K 4096 | V 4096

    // staging offsets: thread t stages K granule t and V granule t (R9 swizzle)
    const int sg = t;
    const int kO = (sg >> 3) * 64 + (((sg & 7) ^ ((sg >> 3) & 7)) * 8);
    const int wg = sg & 63;
    const int vO = (sg >> 6) * 512 + ((wg ^ ((wg >> 3) & 7)) * 8);
    const int lB = w * 512;                            // shorts (wave-uniform)

    // read offsets (R9-verified)
    const int oK0 = cl * 64 + (((quad)     ^ c7) * 8);
    const int oK1 = cl * 64 + (((quad + 4) ^ c7) * 8);
    const int oV0 = cl * 64 + (((quad * 2)     ^ c7) * 8);
    const int oV1 = cl * 64 + (((quad * 2 + 1) ^ c7) * 8);

    const int mrel = (w & 3) * 16 + cl;                // diag row rel. chunk base

    #pragma unroll 1                                   // R6 lesson: no state merge
    for (int hb = 0; hb < 2; ++hb) {
        const int bb = hb ? (15 - pp) : pp;            // 128-row band index
        const int nchB = 2 * bb + 2;                   // staged 64-kv chunks
        const int myLast = 2 * bb + (w >> 2);          // last chunk this wave computes
        const int m0w = bb * 128 + w * 16;

        bf16x8 qf0, qf1;
        {
            const unsigned short* qa = Qb + (size_t)(m0w + cl) * 64 + quad * 8;
            qf0 = *(const bf16x8*)(qa);
            qf1 = *(const bf16x8*)(qa + 32);
        }

        f32x4 o[4] = {};
        float lps = 0.f;

        // stage chunk 0 into buf 0
        {
            unsigned short* s = &KVs[0][0];
            g2lds16(Kb + kO, s + lB);
            g2lds16(Vb + vO, s + 4096 + lB);
        }

        for (int c = 0; c < nchB; ++c) {
            __syncthreads();                           // buf[c&1] ready
            if (c + 1 < nchB) {
                unsigned short* s = &KVs[(c + 1) & 1][0];
                g2lds16(Kb + (size_t)(c + 1) * 4096 + kO, s + lB);
                g2lds16(Vb + (size_t)(c + 1) * 4096 + vO, s + 4096 + lB);
            }
            if (c > myLast) continue;                  // wave-uniform skip
            const unsigned short* Kl = &KVs[c & 1][0];
            const unsigned short* Vl = Kl + 4096;
            const bool masked = (c == myLast);

            bf16x8 kf0[4], kf1[4];
            #pragma unroll
            for (int kt = 0; kt < 4; ++kt) {
                kf0[kt] = *(const bf16x8*)(Kl + kt * 1024 + oK0);
                kf1[kt] = *(const bf16x8*)(Kl + kt * 1024 + oK1);
            }
            f32x4 st[4] = {};
            #pragma unroll
            for (int kt = 0; kt < 4; ++kt) {
                st[kt] = __builtin_amdgcn_mfma_f32_16x16x32_bf16(kf0[kt], qf0, st[kt], 0, 0, 0);
                st[kt] = __builtin_amdgcn_mfma_f32_16x16x32_bf16(kf1[kt], qf1, st[kt], 0, 0, 0);
            }

            short4v pb[4];
            #pragma unroll
            for (int kt = 0; kt < 4; ++kt) {
                float p0, p1, p2, p3;
                if (masked) {
                    const int lk = kt * 16 + quad * 4;
                    p0 = (lk     <= mrel) ? E2(st[kt][0]) : 0.f;
                    p1 = (lk + 1 <= mrel) ? E2(st[kt][1]) : 0.f;
                    p2 = (lk + 2 <= mrel) ? E2(st[kt][2]) : 0.f;
                    p3 = (lk + 3 <= mrel) ? E2(st[kt][3]) : 0.f;
                } else {
                    p0 = E2(st[kt][0]);
                    p1 = E2(st[kt][1]);
                    p2 = E2(st[kt][2]);
                    p3 = E2(st[kt][3]);
                }
                lps += (p0 + p1) + (p2 + p3);
                uint2 u = { pk2bf(p0, p1), pk2bf(p2, p3) };
                short4v pv;
                __builtin_memcpy(&pv, &u, 8);
                pb[kt] = pv;
            }

            #pragma unroll
            for (int kt = 0; kt < 4; ++kt) {
                short8v v0 = *(const short8v*)(Vl + kt * 1024 + oV0);  // dt 0,1
                short8v v1 = *(const short8v*)(Vl + kt * 1024 + oV1);  // dt 2,3
                short4v a0 = __builtin_shufflevector(v0, v0, 0, 1, 2, 3);
                short4v a1 = __builtin_shufflevector(v0, v0, 4, 5, 6, 7);
                short4v a2 = __builtin_shufflevector(v1, v1, 0, 1, 2, 3);
                short4v a3 = __builtin_shufflevector(v1, v1, 4, 5, 6, 7);
                o[0] = __builtin_amdgcn_mfma_f32_16x16x16bf16_1k(a0, pb[kt], o[0], 0, 0, 0);
                o[1] = __builtin_amdgcn_mfma_f32_16x16x16bf16_1k(a1, pb[kt], o[1], 0, 0, 0);
                o[2] = __builtin_amdgcn_mfma_f32_16x16x16bf16_1k(a2, pb[kt], o[2], 0, 0, 0);
                o[3] = __builtin_amdgcn_mfma_f32_16x16x16bf16_1k(a3, pb[kt], o[3], 0, 0, 0);
            }
        }
        __syncthreads();                               // buf reuse across bands

        lps += __shfl_xor(lps, 16);
        lps += __shfl_xor(lps, 32);
        const float inv = 1.0f / lps;
        #pragma unroll
        for (int dt = 0; dt < 4; ++dt) {
            f32x4 r = o[dt];
            r[0] *= inv; r[1] *= inv; r[2] *= inv; r[3] *= inv;
            *(f32x4*)(Ob + (size_t)(m0w + cl) * 64 + dt * 16 + quad * 4) = r;
        }
    }
}

extern "C" void kernel_launch(void* const* d_in, const int* in_sizes, int n_in,
                              void* d_out, int out_size, void* d_ws, size_t ws_size,
                              hipStream_t stream) {
    const float* x  = (const float*)d_in[0];
    const float* Wq = (const float*)d_in[1];
    const float* Wk = (const float*)d_in[2];
    const float* Wv = (const float*)d_in[3];
    float* out = (float*)d_out;

    // ws: xb 8MB | wc 6MB | QKV natural 24MB | VT3 8MB = 46MB
    unsigned short* xb  = (unsigned short*)d_ws;
    unsigned short* wc  = xb + (size_t)4096 * 1024;
    unsigned short* qkv = wc + (size_t)3 * 1024 * 1024;
    unsigned short* vt  = qkv + (size_t)3 * 4096 * 1024;

    hipLaunchKernelGGL(cast_all, dim3(7168), dim3(256), 0, stream, x, Wq, Wk, Wv, xb, wc);
    hipLaunchKernelGGL(gemm_qkv, dim3(8, 32, 3), dim3(256), 0, stream, xb, wc, qkv);
    hipLaunchKernelGGL(vtrans, dim3(16, 32), dim3(256), 0, stream, qkv + (size_t)2 * 4096 * 1024, vt);
    hipLaunchKernelGGL(attn, dim3(256), dim3(512), 0, stream, qkv, vt, out);
}